// Round 14
// baseline (780.544 us; speedup 1.0000x reference)
//
#include <hip/hip_runtime.h>
#include <hip/hip_bf16.h>
#include <math.h>

#define NATOMS 1024          // B*A
#define NGRID  6912          // B*NG
#define NNODES 7936
#define NG_PER 1728
#define KA 8
#define KG 32
#define CODE 64
#define HID 128
#define NT 1024              // gauss@Wg lookup-table intervals over d in [0,5]

typedef __hip_bfloat16 bf16;
typedef unsigned long long u64;
typedef unsigned int u32;

// Fallback workspace allocated at library load (legal: outside kernel_launch).
static void* g_buf = nullptr;
__attribute__((constructor)) static void _alloc_ws(){
  if (hipMalloc(&g_buf, (size_t)24 * 1024 * 1024) != hipSuccess) g_buf = nullptr;
}

// dtype-agnostic float load: element i of buffer p, fp32 if f32!=0 else bf16
__device__ __forceinline__ float ldf(const void* p, size_t i, int f32){
  return f32 ? ((const float*)p)[i] : __bfloat162float(((const bf16*)p)[i]);
}

// dtype-agnostic int load: mode 0=int32, 1=int64(LE), 2=f32, 3=bf16
__device__ __forceinline__ int ldt(const void* p, int i, int mode){
  switch(mode){
    case 1:  return ((const int*)p)[2*i];
    case 2:  return (int)((const float*)p)[i];
    case 3:  return (int)__bfloat162float(((const bf16*)p)[i]);
    default: return ((const int*)p)[i];
  }
}

// ---------- block 0: pos dtype detect; block 1: types dtype + gauss consts ----------
__global__ void k0(const unsigned short* __restrict__ posu,
                   const unsigned short* __restrict__ typu,
                   int* __restrict__ flag, float* __restrict__ offc){
  if (blockIdx.x == 0){
    __shared__ int scnt;
    int t = threadIdx.x;               // 256 threads
    if (t == 0) scnt = 0;
    __syncthreads();
    int c = 0;
    for (int q = 0; q < 12; q++){
      unsigned short u = posu[t + 256*q];
      int e = (u >> 7) & 0xFF;
      if (e >= 140) c++;
    }
    atomicAdd(&scnt, c);
    __syncthreads();
    if (t == 0) flag[0] = (scnt > 16) ? 1 : 0;
  } else {
    if (threadIdx.x == 0){
      int oddHigh = 0, evenHigh = 0, quadZero = 1;
      for (int k = 0; k < 16; k++){
        unsigned short o = typu[2*k+1], e = typu[2*k];
        if (o >= 0x3F00 && o <= 0x4200) oddHigh++;
        if (e >= 0x3F00 && e <= 0x4200) evenHigh++;
      }
      for (int k = 0; k < 16; k++) if (typu[4*k+2] != 0) quadZero = 0;
      int mode;
      if (oddHigh >= 8) mode = (evenHigh >= 8) ? 3 : 2;   // bf16 : f32
      else              mode = quadZero ? 1 : 0;          // int64 : int32
      flag[1] = mode;
    }
    int k = (int)threadIdx.x - 64;
    if (k >= 0 && k < 20){
      double step = log(6.0) / 19.0;
      double offk = exp((double)k * step) - 1.0;
      int km = (k == 0) ? 1 : k;
      double d = (exp((double)km * step) - 1.0) - (exp((double)(km - 1) * step) - 1.0);
      offc[k]      = (float)offk;
      offc[20 + k] = (float)(-0.5 / (d * d));
    }
  }
}

// ---------- preamble (low-VGPR only — weight work lives in k_wt; r6 lesson):
//   blocks 0..1983 init; 1984..2239 atom kNN; 2240..3967 grid kNN
//   (f64 rank-select, bit-identical to min-extraction);
//   3968..4959 layer-0 fold = one-hot gather (bit-identical to GEMM over
//   one-hot h0; low-VGPR, rides this grid — saves a launch + gap). ----------
__global__ void __launch_bounds__(256) k_pre(const void* __restrict__ pos,
    const void* __restrict__ types, const int* __restrict__ flag,
    float* __restrict__ node_pos, float* __restrict__ h0,
    int* __restrict__ nbrA, int* __restrict__ nbrG,
    const void* __restrict__ W1, float* __restrict__ Xd, float* __restrict__ Xs){
  #pragma clang fp contract(off)
  __shared__ __attribute__((aligned(16))) u64 sK[4][256];   // 8 KB, wave-private rows
  int f32 = flag[0];
  int b = blockIdx.x;
  int t = threadIdx.x;
  if (b < 1984){
    // ---- init: node_pos (f32) + h0 one-hot ----
    int tm = flag[1];
    int idx = b * 256 + t;             // < NNODES*64
    if (idx < NNODES){
      if (idx < NATOMS){
        node_pos[idx*3+0] = ldf(pos, idx*3+0, f32);
        node_pos[idx*3+1] = ldf(pos, idx*3+1, f32);
        node_pos[idx*3+2] = ldf(pos, idx*3+2, f32);
      } else {
        int cell = (idx - NATOMS) % NG_PER;
        int ix = cell / 144, iy = (cell / 12) % 12, iz = cell % 12;
        node_pos[idx*3+0] = -8.25f + 1.5f * ix;
        node_pos[idx*3+1] = -8.25f + 1.5f * iy;
        node_pos[idx*3+2] = -8.25f + 1.5f * iz;
      }
    }
    int node = idx >> 6, c = idx & 63;
    float v = 0.f;
    if (node < NATOMS && c == ldt(types, node, tm)) v = 1.f;
    h0[idx] = v;
  } else if (b < 1984 + 256){
    // ---- atom-atom kNN (K=8): u64 key = (f32 d2 bits << 8) | idx (exact lex) ----
    int i = (b - 1984) * 4 + (t >> 6);
    int bb = i >> 8, li = i & 255;
    int l = t & 63;
    float px = ldf(pos,3*i,f32), py = ldf(pos,3*i+1,f32), pz = ldf(pos,3*i+2,f32);
    u64 vals[4];
    for (int q = 0; q < 4; q++){
      int c = l + 64*q;
      int j = (bb << 8) + c;
      float dx = ldf(pos,3*j+0,f32) - px;
      float dy = ldf(pos,3*j+1,f32) - py;
      float dz = ldf(pos,3*j+2,f32) - pz;
      float d2 = (dx*dx + dy*dy) + dz*dz;
      vals[q] = (c == li) ? ~0ull : (((u64)__float_as_uint(d2) << 8) | (unsigned)c);
    }
    for (int it = 0; it < KA; it++){
      u64 v = vals[0];
      for (int q = 1; q < 4; q++) if (vals[q] < v) v = vals[q];
      for (int m = 1; m < 64; m <<= 1){
        u64 ov = __shfl_xor(v, m);
        if (ov < v) v = ov;
      }
      int widx = (int)(v & 0xFF);
      if (l == 0) nbrA[i*KA + it] = (bb << 8) + widx;
      if ((widx & 63) == l) vals[widx >> 6] = ~0ull;
    }
  } else if (b < 3968){
    // ---- grid->atom kNN (K=32), f64 keys; key = (f64 bits & ~0xFF) | idx.
    //      rank-based: rank(q) = #{keys < key_q}; rank<32 -> nbrG[gi*32+rank]. ----
    int w  = t >> 6;
    int gi = (b - 2240) * 4 + w;
    int bb = gi / NG_PER, cell = gi % NG_PER;
    int ix = cell / 144, iy = (cell / 12) % 12, iz = cell % 12;
    double px = -8.25 + 1.5 * ix;
    double py = -8.25 + 1.5 * iy;
    double pz = -8.25 + 1.5 * iz;
    int l = t & 63;
    u64* sk = &sK[w][0];
    u64 vals[4];
    #pragma unroll
    for (int q = 0; q < 4; q++){
      int c = l + 64*q;
      int j = (bb << 8) + c;
      double dx = px - (double)ldf(pos,3*j+0,f32);
      double dy = py - (double)ldf(pos,3*j+1,f32);
      double dz = pz - (double)ldf(pos,3*j+2,f32);
      double d2 = dx*dx + dy*dy + dz*dz;
      u64 key = ((u64)__double_as_longlong(d2) & ~0xFFull) | (unsigned)c;
      vals[q] = key;
      sk[c] = key;
    }
    __syncthreads();
    int r0 = 0, r1 = 0, r2 = 0, r3 = 0;
    #pragma unroll 4
    for (int j = 0; j < 256; j += 2){
      ulonglong2 kk = *(const ulonglong2*)&sk[j];
      r0 += (kk.x < vals[0]); r0 += (kk.y < vals[0]);
      r1 += (kk.x < vals[1]); r1 += (kk.y < vals[1]);
      r2 += (kk.x < vals[2]); r2 += (kk.y < vals[2]);
      r3 += (kk.x < vals[3]); r3 += (kk.y < vals[3]);
    }
    int base = (bb << 8) + l;
    if (r0 < KG) nbrG[gi*KG + r0] = base;
    if (r1 < KG) nbrG[gi*KG + r1] = base + 64;
    if (r2 < KG) nbrG[gi*KG + r2] = base + 128;
    if (r3 < KG) nbrG[gi*KG + r3] = base + 192;
  } else {
    // ---- layer-0 fold gather: Xd[node][c] = node<NATOMS ? W1dst[ty][c] : 0;
    //      Xs[atom][c] = W1src[ty][c]. ----
    int tm = flag[1];
    int idx = (b - 3968) * 1024 + t;
    #pragma unroll
    for (int i = 0; i < 4; i++, idx += 256){
      int node = idx >> 7, c = idx & 127;
      if (node < NATOMS){
        int ty = ldt(types, node, tm);
        Xd[idx] = ldf(W1, (size_t)64*128 + (size_t)ty*128 + c, f32);
        Xs[idx] = ldf(W1, (size_t)ty*128 + c, f32);
      } else if (node < NNODES){
        Xd[idx] = 0.f;
      }
    }
  }
}

// ---------- weight-only per-layer work, all 4 layers in one small launch:
//   block b: layer = b/129, sub = b%129.
//   sub==0: Wg = eW@W1c, b1p = b1 + eb@W1c;  sub 1..128: Tt[l] float2 rows. ----------
__global__ void __launch_bounds__(128) k_wt(
    const void* __restrict__ W1, const void* __restrict__ b1,
    const void* __restrict__ eW, const void* __restrict__ eb,
    const int* __restrict__ flag, const float* __restrict__ offc,
    float* __restrict__ Wg, float* __restrict__ b1p, float2* __restrict__ Tt)
{
  __shared__ __attribute__((aligned(16))) float sA[1344];
  __shared__ float sB[192];
  int f32 = flag[0];
  int t = threadIdx.x;
  int b = blockIdx.x;
  int layer = b / 129, sub = b - layer * 129;
  size_t wl  = (size_t)layer*192*128;
  size_t eWo = (size_t)layer*20*64, ebo = (size_t)layer*64;
  size_t b1o = (size_t)layer*128;
  float w[64];
  #pragma unroll
  for (int k = 0; k < 64; k++) w[k] = ldf(W1, wl + (size_t)128*128 + (size_t)k*128 + t, f32);
  for (int i = t; i < 20*64; i += 128) sA[i] = ldf(eW, eWo + i, f32);
  if (sub == 0){
    if (t < 64) sA[1280 + t] = ldf(eb, ebo + t, f32);
    __syncthreads();
    for (int g = 0; g < 20; g++){
      float acc = 0.f;
      #pragma unroll
      for (int k4 = 0; k4 < 16; k4++){
        float4 e = *(const float4*)&sA[g*64 + 4*k4];
        acc = fmaf(e.x, w[4*k4+0], acc); acc = fmaf(e.y, w[4*k4+1], acc);
        acc = fmaf(e.z, w[4*k4+2], acc); acc = fmaf(e.w, w[4*k4+3], acc);
      }
      Wg[layer*20*128 + g*128 + t] = acc;
    }
    float acc = ldf(b1, b1o + t, f32);
    #pragma unroll
    for (int k4 = 0; k4 < 16; k4++){
      float4 e = *(const float4*)&sA[1280 + 4*k4];
      acc = fmaf(e.x, w[4*k4+0], acc); acc = fmaf(e.y, w[4*k4+1], acc);
      acc = fmaf(e.z, w[4*k4+2], acc); acc = fmaf(e.w, w[4*k4+3], acc);
    }
    b1p[layer*128 + t] = acc;
  } else {
    // Tt table rows r0..r0+7 (float2: (f[r],f[r+1])); 9 vals so .y spans rows
    int r0 = (sub - 1) * 8;
    for (int i = t; i < 180; i += 128){
      int row = i / 20, k = i - row*20;
      float d  = (float)(r0 + row) * (5.0f / (float)NT);
      float dd = d - offc[k];
      sB[i] = expf(offc[20 + k] * dd * dd);
    }
    __syncthreads();
    float wg[20];
    #pragma unroll
    for (int gk = 0; gk < 20; gk++){
      float acc = 0.f;
      #pragma unroll
      for (int k4 = 0; k4 < 16; k4++){
        float4 e = *(const float4*)&sA[gk*64 + 4*k4];
        acc = fmaf(e.x, w[4*k4+0], acc); acc = fmaf(e.y, w[4*k4+1], acc);
        acc = fmaf(e.z, w[4*k4+2], acc); acc = fmaf(e.w, w[4*k4+3], acc);
      }
      wg[gk] = acc;
    }
    float v[9];
    #pragma unroll
    for (int r = 0; r < 9; r++){
      float acc = 0.f;
      #pragma unroll
      for (int k = 0; k < 20; k++) acc = fmaf(sB[r*20 + k], wg[k], acc);
      v[r] = acc;
    }
    #pragma unroll
    for (int r = 0; r < 8; r++)
      Tt[(size_t)layer*NT*128 + (size_t)(r0 + r)*128 + t] = make_float2(v[r], v[r+1]);
  }
}

// ---------- aggregation: Sbuf[node][tt] = (1/K) sum_e relu(Xd + Xs[src] + b1p + lerp(Tt,d_e)) ----------
__global__ void __launch_bounds__(256) k_aggr(const float* __restrict__ Xs,
    const float* __restrict__ Xd, const int* __restrict__ nbrA,
    const int* __restrict__ nbrG, const float* __restrict__ node_pos,
    const float2* __restrict__ Tt, const float* __restrict__ b1p,
    float* __restrict__ Sbuf)
{
  __shared__ __attribute__((aligned(16))) int   sN[256];
  __shared__ __attribute__((aligned(16))) float sX[256];
  int t = threadIdx.x;            // 256
  int b = blockIdx.x;
  int KK, node0; const int* nbr;
  if (b < 32){ KK = 8;  node0 = b*32;              nbr = nbrA + b*256; }
  else       { KK = 32; node0 = NATOMS + (b-32)*8; nbr = nbrG + (size_t)(b-32)*256; }
  {
    int src = nbr[t];
    sN[t] = src;
    int node = node0 + ((b < 32) ? (t >> 3) : (t >> 5));
    float dx = node_pos[src*3+0] - node_pos[node*3+0];
    float dy = node_pos[src*3+1] - node_pos[node*3+1];
    float dz = node_pos[src*3+2] - node_pos[node*3+2];
    float dist = fminf(sqrtf(dx*dx + dy*dy + dz*dz), 5.0f);
    sX[t] = dist * ((float)NT / 5.0f);
  }
  int g = t >> 7, tt = t & 127;
  float b1v = b1p[tt];
  __syncthreads();
  float rK = 1.f / KK;
  int nLoc = (b < 32) ? 16 : 4;
  int nbase = g * nLoc;
  for (int n = 0; n < nLoc; n++){
    int node = node0 + nbase + n;
    float zb = Xd[(size_t)node*128 + tt] + b1v;
    float S = 0.f;
    int ebase = (nbase + n) * KK;
    for (int e = 0; e < KK; e += 4){
      int i0 = ebase + e;
      int4   sv = *(const int4*)&sN[i0];
      float4 xv = *(const float4*)&sX[i0];
      int ia0 = (int)xv.x; if (ia0 > NT-1) ia0 = NT-1;
      int ia1 = (int)xv.y; if (ia1 > NT-1) ia1 = NT-1;
      int ia2 = (int)xv.z; if (ia2 > NT-1) ia2 = NT-1;
      int ia3 = (int)xv.w; if (ia3 > NT-1) ia3 = NT-1;
      float f0 = xv.x - (float)ia0;
      float f1 = xv.y - (float)ia1;
      float f2 = xv.z - (float)ia2;
      float f3 = xv.w - (float)ia3;
      float2 w0 = Tt[(size_t)ia0*128 + tt];
      float2 w1 = Tt[(size_t)ia1*128 + tt];
      float2 w2 = Tt[(size_t)ia2*128 + tt];
      float2 w3 = Tt[(size_t)ia3*128 + tt];
      float a0 = zb + Xs[(size_t)sv.x*128 + tt] + fmaf(f0, w0.y - w0.x, w0.x);
      float a1 = zb + Xs[(size_t)sv.y*128 + tt] + fmaf(f1, w1.y - w1.x, w1.x);
      float a2 = zb + Xs[(size_t)sv.z*128 + tt] + fmaf(f2, w2.y - w2.x, w2.x);
      float a3 = zb + Xs[(size_t)sv.w*128 + tt] + fmaf(f3, w3.y - w3.x, w3.x);
      S += fmaxf(a0,0.f) + fmaxf(a1,0.f) + fmaxf(a2,0.f) + fmaxf(a3,0.f);
    }
    Sbuf[(size_t)node*128 + tt] = S * rK;
  }
}

// ---------- merged output + next-layer fold — LDS-FREE out phase.
//   496 blocks x 512 thr, 16 rows/block; each wave = one row pair.
//   r13's staged version was 1 block/CU (248 blocks < 256 CUs) = 2 waves/SIMD,
//   ~99% stall. Here: no sW2/sS stage (W2[k][c] read coalesced from L2 —
//   32 KB fully cached, ~130 MB/layer = ~4 µs at L2 BW; S rows via
//   wave-uniform float4 broadcasts), LDS only sH 4 KB -> 2 blocks/CU =
//   4 waves/SIMD, and no stage barrier. W2-stage-replication lesson (r8)
//   doesn't apply: there is no stage. FMA order per output element is the
//   same ascending-k chain -> bit-identical results.
//   Fold phase (doFold): Xd rows = sH @ W1dst(l+1); blocks<64 also Xs. ----------
__global__ void __launch_bounds__(512) k_outfold(const float* __restrict__ hin,
    const float* __restrict__ Sbuf,
    const void* __restrict__ W2, const void* __restrict__ b2,
    const void* __restrict__ lng, const void* __restrict__ lnb,
    size_t w2o, size_t b2o, size_t lno,
    const void* __restrict__ W1, size_t wlNext, int doFold,
    const int* __restrict__ flag,
    float* __restrict__ Xd, float* __restrict__ Xs,
    float* __restrict__ hout, float* __restrict__ out, int writeOut)
{
  __shared__ __attribute__((aligned(16))) float sH[16*64];     // 4 KB only
  int f32 = flag[0];
  int t = threadIdx.x;            // 512
  int r0 = blockIdx.x * 16;
  int w = t >> 6, c = t & 63;     // 8 waves; wave w owns rows w*2, w*2+1
  int rr = w * 2;
  // early independent hin prefetch (this wave's 2 rows)
  float hv0 = hin[(size_t)(r0 + rr + 0)*64 + c];
  float hv1 = hin[(size_t)(r0 + rr + 1)*64 + c];
  float b2v = ldf(b2, b2o + c, f32);
  float gv  = ldf(lng, lno + c, f32);
  float bv  = ldf(lnb, lno + c, f32);
  // ---- out phase: GEMV straight from L2 (W2 coalesced; S wave-uniform) ----
  {
    float a0 = 0.f, a1 = 0.f;
    const float* s0 = Sbuf + (size_t)(r0 + rr) * 128;
    const float* s1 = s0 + 128;
    #pragma unroll
    for (int kq = 0; kq < 32; kq++){
      float4 sv0 = *(const float4*)(s0 + 4*kq);
      float4 sv1 = *(const float4*)(s1 + 4*kq);
      float w0 = ldf(W2, w2o + (size_t)(4*kq+0)*64 + c, f32);
      float w1 = ldf(W2, w2o + (size_t)(4*kq+1)*64 + c, f32);
      float w2v = ldf(W2, w2o + (size_t)(4*kq+2)*64 + c, f32);
      float w3 = ldf(W2, w2o + (size_t)(4*kq+3)*64 + c, f32);
      a0 = fmaf(sv0.x, w0, a0);
      a0 = fmaf(sv0.y, w1, a0);
      a0 = fmaf(sv0.z, w2v, a0);
      a0 = fmaf(sv0.w, w3, a0);
      a1 = fmaf(sv1.x, w0, a1);
      a1 = fmaf(sv1.y, w1, a1);
      a1 = fmaf(sv1.z, w2v, a1);
      a1 = fmaf(sv1.w, w3, a1);
    }
    {
      int node = r0 + rr;
      float x = hv0 + a0 + b2v;
      float s = x;
      #pragma unroll
      for (int m = 1; m < 64; m <<= 1) s += __shfl_xor(s, m);
      float mu = s * (1.f/64.f);
      float d = x - mu;
      float v = d * d;
      #pragma unroll
      for (int m = 1; m < 64; m <<= 1) v += __shfl_xor(v, m);
      v *= (1.f/64.f);
      float o = d / sqrtf(v + 1e-5f) * gv + bv;
      hout[(size_t)node*64 + c] = o;
      sH[rr*64 + c] = o;
      if (writeOut && node >= NATOMS) out[(size_t)(node - NATOMS)*64 + c] = o;
    }
    {
      int node = r0 + rr + 1;
      float x = hv1 + a1 + b2v;
      float s = x;
      #pragma unroll
      for (int m = 1; m < 64; m <<= 1) s += __shfl_xor(s, m);
      float mu = s * (1.f/64.f);
      float d = x - mu;
      float v = d * d;
      #pragma unroll
      for (int m = 1; m < 64; m <<= 1) v += __shfl_xor(v, m);
      v *= (1.f/64.f);
      float o = d / sqrtf(v + 1e-5f) * gv + bv;
      hout[(size_t)node*64 + c] = o;
      sH[(rr+1)*64 + c] = o;
      if (writeOut && node >= NATOMS) out[(size_t)(node - NATOMS)*64 + c] = o;
    }
  }
  if (!doFold) return;
  __syncthreads();
  int col = t & 127, q = t >> 7;   // 4 quarters x 4 rows = 16 rows
  int rbase = q * 4;
  {
    float w1r[64];
    #pragma unroll
    for (int k = 0; k < 64; k++)
      w1r[k] = ldf(W1, wlNext + (size_t)64*128 + (size_t)k*128 + col, f32);
    {
      int r = rbase;
      float a0 = 0.f, a1 = 0.f, a2 = 0.f, a3 = 0.f;
      #pragma unroll
      for (int k4 = 0; k4 < 16; k4++){
        float4 v0 = *(const float4*)&sH[(r+0)*64 + 4*k4];
        float4 v1 = *(const float4*)&sH[(r+1)*64 + 4*k4];
        float4 v2 = *(const float4*)&sH[(r+2)*64 + 4*k4];
        float4 v3 = *(const float4*)&sH[(r+3)*64 + 4*k4];
        a0 = fmaf(v0.x, w1r[4*k4+0], a0); a0 = fmaf(v0.y, w1r[4*k4+1], a0);
        a0 = fmaf(v0.z, w1r[4*k4+2], a0); a0 = fmaf(v0.w, w1r[4*k4+3], a0);
        a1 = fmaf(v1.x, w1r[4*k4+0], a1); a1 = fmaf(v1.y, w1r[4*k4+1], a1);
        a1 = fmaf(v1.z, w1r[4*k4+2], a1); a1 = fmaf(v1.w, w1r[4*k4+3], a1);
        a2 = fmaf(v2.x, w1r[4*k4+0], a2); a2 = fmaf(v2.y, w1r[4*k4+1], a2);
        a2 = fmaf(v2.z, w1r[4*k4+2], a2); a2 = fmaf(v2.w, w1r[4*k4+3], a2);
        a3 = fmaf(v3.x, w1r[4*k4+0], a3); a3 = fmaf(v3.y, w1r[4*k4+1], a3);
        a3 = fmaf(v3.z, w1r[4*k4+2], a3); a3 = fmaf(v3.w, w1r[4*k4+3], a3);
      }
      Xd[(size_t)(r0 + r + 0)*128 + col] = a0;
      Xd[(size_t)(r0 + r + 1)*128 + col] = a1;
      Xd[(size_t)(r0 + r + 2)*128 + col] = a2;
      Xd[(size_t)(r0 + r + 3)*128 + col] = a3;
    }
  }
  if (blockIdx.x < 64){
    float w1s[64];
    #pragma unroll
    for (int k = 0; k < 64; k++)
      w1s[k] = ldf(W1, wlNext + (size_t)k*128 + col, f32);
    {
      int r = rbase;
      float a0 = 0.f, a1 = 0.f, a2 = 0.f, a3 = 0.f;
      #pragma unroll
      for (int k4 = 0; k4 < 16; k4++){
        float4 v0 = *(const float4*)&sH[(r+0)*64 + 4*k4];
        float4 v1 = *(const float4*)&sH[(r+1)*64 + 4*k4];
        float4 v2 = *(const float4*)&sH[(r+2)*64 + 4*k4];
        float4 v3 = *(const float4*)&sH[(r+3)*64 + 4*k4];
        a0 = fmaf(v0.x, w1s[4*k4+0], a0); a0 = fmaf(v0.y, w1s[4*k4+1], a0);
        a0 = fmaf(v0.z, w1s[4*k4+2], a0); a0 = fmaf(v0.w, w1s[4*k4+3], a0);
        a1 = fmaf(v1.x, w1s[4*k4+0], a1); a1 = fmaf(v1.y, w1s[4*k4+1], a1);
        a1 = fmaf(v1.z, w1s[4*k4+2], a1); a1 = fmaf(v1.w, w1s[4*k4+3], a1);
        a2 = fmaf(v2.x, w1s[4*k4+0], a2); a2 = fmaf(v2.y, w1s[4*k4+1], a2);
        a2 = fmaf(v2.z, w1s[4*k4+2], a2); a2 = fmaf(v2.w, w1s[4*k4+3], a2);
        a3 = fmaf(v3.x, w1s[4*k4+0], a3); a3 = fmaf(v3.y, w1s[4*k4+1], a3);
        a3 = fmaf(v3.z, w1s[4*k4+2], a3); a3 = fmaf(v3.w, w1s[4*k4+3], a3);
      }
      Xs[(size_t)(r0 + r + 0)*128 + col] = a0;
      Xs[(size_t)(r0 + r + 1)*128 + col] = a1;
      Xs[(size_t)(r0 + r + 2)*128 + col] = a2;
      Xs[(size_t)(r0 + r + 3)*128 + col] = a3;
    }
  }
}

extern "C" void kernel_launch(void* const* d_in, const int* in_sizes, int n_in,
                              void* d_out, int out_size, void* d_ws, size_t ws_size,
                              hipStream_t stream) {
  const void* pos    = d_in[0];
  const void* types  = d_in[1];
  // d_in[2] = batch (unused by the math)
  const void* edge_W = d_in[3];
  const void* edge_b = d_in[4];
  const void* W1     = d_in[5];
  const void* b1     = d_in[6];
  const void* W2     = d_in[7];
  const void* b2     = d_in[8];
  const void* lng    = d_in[9];
  const void* lnb    = d_in[10];

  const size_t NEED = (size_t)20 * 1024 * 1024;
  char* w = (ws_size >= NEED) ? (char*)d_ws : (char*)g_buf;
  if (w == nullptr) w = (char*)d_ws;   // last resort

  size_t o = 0;
  auto alloc = [&](size_t bytes)->char*{
    char* r = w + o; o = (o + bytes + 255) & ~(size_t)255; return r;
  };
  float*  node_pos = (float*) alloc((size_t)NNODES*3*4);
  float*  hA       = (float*) alloc((size_t)NNODES*CODE*4);
  float*  hB       = (float*) alloc((size_t)NNODES*CODE*4);
  float*  Xs       = (float*) alloc((size_t)NATOMS*HID*4);
  float*  Xd       = (float*) alloc((size_t)NNODES*HID*4);
  float*  Sbuf     = (float*) alloc((size_t)NNODES*HID*4);
  int*    nbrA     = (int*)   alloc((size_t)NATOMS*KA*4);
  int*    nbrG     = (int*)   alloc((size_t)NGRID*KG*4);
  float*  offc     = (float*) alloc(64*4);
  float*  Wg       = (float*) alloc((size_t)4*20*HID*4);
  float*  b1p      = (float*) alloc((size_t)4*HID*4);
  int*    flag     = (int*)   alloc(64*4);
  float2* Tt       = (float2*)alloc((size_t)4*NT*HID*8);   // 4 layers x 1.05 MB

  k0<<<2, 256, 0, stream>>>((const unsigned short*)pos,
                            (const unsigned short*)types, flag, offc);
  k_wt<<<4*129, 128, 0, stream>>>(W1, b1, edge_W, edge_b, flag, offc,
                                  Wg, b1p, Tt);
  // k_pre includes the layer-0 fold gather in blocks 3968..4959
  k_pre<<<3968 + 992, 256, 0, stream>>>(pos, types, flag, node_pos, hA,
                                        nbrA, nbrG, W1, Xd, Xs);

  float* hin = hA; float* hout = hB;
  for (int l = 0; l < 4; l++){
    size_t w2o = (size_t)l*128*64;
    size_t b2o = (size_t)l*64, lno = (size_t)l*64;
    size_t wlN = (size_t)(l+1)*192*128;
    k_aggr<<<32 + NGRID/8, 256, 0, stream>>>(Xs, Xd, nbrA, nbrG, node_pos,
                                             Tt + (size_t)l*NT*HID, b1p + l*HID,
                                             Sbuf);
    k_outfold<<<NNODES/16, 512, 0, stream>>>(hin, Sbuf, W2, b2, lng, lnb,
                                             w2o, b2o, lno,
                                             W1, wlN, (l < 3) ? 1 : 0,
                                             flag, Xd, Xs,
                                             hout, (float*)d_out, (l == 3) ? 1 : 0);
    float* tmp = hin; hin = hout; hout = tmp;
  }
}

// Round 15
// 304.378 us; speedup vs baseline: 2.5644x; 2.5644x over previous
//
#include <hip/hip_runtime.h>
#include <hip/hip_bf16.h>
#include <math.h>

#define NATOMS 1024          // B*A
#define NGRID  6912          // B*NG
#define NNODES 7936
#define NG_PER 1728
#define KA 8
#define KG 32
#define CODE 64
#define HID 128
#define NT 1024              // gauss@Wg lookup-table intervals over d in [0,5]

typedef __hip_bfloat16 bf16;
typedef unsigned long long u64;
typedef unsigned int u32;

// Fallback workspace allocated at library load (legal: outside kernel_launch).
static void* g_buf = nullptr;
__attribute__((constructor)) static void _alloc_ws(){
  if (hipMalloc(&g_buf, (size_t)24 * 1024 * 1024) != hipSuccess) g_buf = nullptr;
}

// dtype-agnostic float load: element i of buffer p, fp32 if f32!=0 else bf16
__device__ __forceinline__ float ldf(const void* p, size_t i, int f32){
  return f32 ? ((const float*)p)[i] : __bfloat162float(((const bf16*)p)[i]);
}

// dtype-agnostic int load: mode 0=int32, 1=int64(LE), 2=f32, 3=bf16
__device__ __forceinline__ int ldt(const void* p, int i, int mode){
  switch(mode){
    case 1:  return ((const int*)p)[2*i];
    case 2:  return (int)((const float*)p)[i];
    case 3:  return (int)__bfloat162float(((const bf16*)p)[i]);
    default: return ((const int*)p)[i];
  }
}

// ---------- block 0: pos dtype detect; block 1: types dtype + gauss consts ----------
__global__ void k0(const unsigned short* __restrict__ posu,
                   const unsigned short* __restrict__ typu,
                   int* __restrict__ flag, float* __restrict__ offc){
  if (blockIdx.x == 0){
    __shared__ int scnt;
    int t = threadIdx.x;               // 256 threads
    if (t == 0) scnt = 0;
    __syncthreads();
    int c = 0;
    for (int q = 0; q < 12; q++){
      unsigned short u = posu[t + 256*q];
      int e = (u >> 7) & 0xFF;
      if (e >= 140) c++;
    }
    atomicAdd(&scnt, c);
    __syncthreads();
    if (t == 0) flag[0] = (scnt > 16) ? 1 : 0;
  } else {
    if (threadIdx.x == 0){
      int oddHigh = 0, evenHigh = 0, quadZero = 1;
      for (int k = 0; k < 16; k++){
        unsigned short o = typu[2*k+1], e = typu[2*k];
        if (o >= 0x3F00 && o <= 0x4200) oddHigh++;
        if (e >= 0x3F00 && e <= 0x4200) evenHigh++;
      }
      for (int k = 0; k < 16; k++) if (typu[4*k+2] != 0) quadZero = 0;
      int mode;
      if (oddHigh >= 8) mode = (evenHigh >= 8) ? 3 : 2;   // bf16 : f32
      else              mode = quadZero ? 1 : 0;          // int64 : int32
      flag[1] = mode;
    }
    int k = (int)threadIdx.x - 64;
    if (k >= 0 && k < 20){
      double step = log(6.0) / 19.0;
      double offk = exp((double)k * step) - 1.0;
      int km = (k == 0) ? 1 : k;
      double d = (exp((double)km * step) - 1.0) - (exp((double)(km - 1) * step) - 1.0);
      offc[k]      = (float)offk;
      offc[20 + k] = (float)(-0.5 / (d * d));
    }
  }
}

// ---------- preamble (low-VGPR only — weight work lives in k_wt; r6 lesson):
//   blocks 0..1983 init; 1984..2239 atom kNN; 2240..3967 grid kNN
//   (f64 rank-select, bit-identical to min-extraction);
//   3968..4959 layer-0 fold = one-hot gather (bit-identical to GEMM over
//   one-hot h0; low-VGPR, rides this grid — saves a launch + gap). ----------
__global__ void __launch_bounds__(256) k_pre(const void* __restrict__ pos,
    const void* __restrict__ types, const int* __restrict__ flag,
    float* __restrict__ node_pos, float* __restrict__ h0,
    int* __restrict__ nbrA, int* __restrict__ nbrG,
    const void* __restrict__ W1, float* __restrict__ Xd, float* __restrict__ Xs){
  #pragma clang fp contract(off)
  __shared__ __attribute__((aligned(16))) u64 sK[4][256];   // 8 KB, wave-private rows
  int f32 = flag[0];
  int b = blockIdx.x;
  int t = threadIdx.x;
  if (b < 1984){
    // ---- init: node_pos (f32) + h0 one-hot ----
    int tm = flag[1];
    int idx = b * 256 + t;             // < NNODES*64
    if (idx < NNODES){
      if (idx < NATOMS){
        node_pos[idx*3+0] = ldf(pos, idx*3+0, f32);
        node_pos[idx*3+1] = ldf(pos, idx*3+1, f32);
        node_pos[idx*3+2] = ldf(pos, idx*3+2, f32);
      } else {
        int cell = (idx - NATOMS) % NG_PER;
        int ix = cell / 144, iy = (cell / 12) % 12, iz = cell % 12;
        node_pos[idx*3+0] = -8.25f + 1.5f * ix;
        node_pos[idx*3+1] = -8.25f + 1.5f * iy;
        node_pos[idx*3+2] = -8.25f + 1.5f * iz;
      }
    }
    int node = idx >> 6, c = idx & 63;
    float v = 0.f;
    if (node < NATOMS && c == ldt(types, node, tm)) v = 1.f;
    h0[idx] = v;
  } else if (b < 1984 + 256){
    // ---- atom-atom kNN (K=8): u64 key = (f32 d2 bits << 8) | idx (exact lex) ----
    int i = (b - 1984) * 4 + (t >> 6);
    int bb = i >> 8, li = i & 255;
    int l = t & 63;
    float px = ldf(pos,3*i,f32), py = ldf(pos,3*i+1,f32), pz = ldf(pos,3*i+2,f32);
    u64 vals[4];
    for (int q = 0; q < 4; q++){
      int c = l + 64*q;
      int j = (bb << 8) + c;
      float dx = ldf(pos,3*j+0,f32) - px;
      float dy = ldf(pos,3*j+1,f32) - py;
      float dz = ldf(pos,3*j+2,f32) - pz;
      float d2 = (dx*dx + dy*dy) + dz*dz;
      vals[q] = (c == li) ? ~0ull : (((u64)__float_as_uint(d2) << 8) | (unsigned)c);
    }
    for (int it = 0; it < KA; it++){
      u64 v = vals[0];
      for (int q = 1; q < 4; q++) if (vals[q] < v) v = vals[q];
      for (int m = 1; m < 64; m <<= 1){
        u64 ov = __shfl_xor(v, m);
        if (ov < v) v = ov;
      }
      int widx = (int)(v & 0xFF);
      if (l == 0) nbrA[i*KA + it] = (bb << 8) + widx;
      if ((widx & 63) == l) vals[widx >> 6] = ~0ull;
    }
  } else if (b < 3968){
    // ---- grid->atom kNN (K=32), f64 keys; key = (f64 bits & ~0xFF) | idx.
    //      rank-based: rank(q) = #{keys < key_q}; rank<32 -> nbrG[gi*32+rank]. ----
    int w  = t >> 6;
    int gi = (b - 2240) * 4 + w;
    int bb = gi / NG_PER, cell = gi % NG_PER;
    int ix = cell / 144, iy = (cell / 12) % 12, iz = cell % 12;
    double px = -8.25 + 1.5 * ix;
    double py = -8.25 + 1.5 * iy;
    double pz = -8.25 + 1.5 * iz;
    int l = t & 63;
    u64* sk = &sK[w][0];
    u64 vals[4];
    #pragma unroll
    for (int q = 0; q < 4; q++){
      int c = l + 64*q;
      int j = (bb << 8) + c;
      double dx = px - (double)ldf(pos,3*j+0,f32);
      double dy = py - (double)ldf(pos,3*j+1,f32);
      double dz = pz - (double)ldf(pos,3*j+2,f32);
      double d2 = dx*dx + dy*dy + dz*dz;
      u64 key = ((u64)__double_as_longlong(d2) & ~0xFFull) | (unsigned)c;
      vals[q] = key;
      sk[c] = key;
    }
    __syncthreads();
    int r0 = 0, r1 = 0, r2 = 0, r3 = 0;
    #pragma unroll 4
    for (int j = 0; j < 256; j += 2){
      ulonglong2 kk = *(const ulonglong2*)&sk[j];
      r0 += (kk.x < vals[0]); r0 += (kk.y < vals[0]);
      r1 += (kk.x < vals[1]); r1 += (kk.y < vals[1]);
      r2 += (kk.x < vals[2]); r2 += (kk.y < vals[2]);
      r3 += (kk.x < vals[3]); r3 += (kk.y < vals[3]);
    }
    int base = (bb << 8) + l;
    if (r0 < KG) nbrG[gi*KG + r0] = base;
    if (r1 < KG) nbrG[gi*KG + r1] = base + 64;
    if (r2 < KG) nbrG[gi*KG + r2] = base + 128;
    if (r3 < KG) nbrG[gi*KG + r3] = base + 192;
  } else {
    // ---- layer-0 fold gather: Xd[node][c] = node<NATOMS ? W1dst[ty][c] : 0;
    //      Xs[atom][c] = W1src[ty][c]. ----
    int tm = flag[1];
    int idx = (b - 3968) * 1024 + t;
    #pragma unroll
    for (int i = 0; i < 4; i++, idx += 256){
      int node = idx >> 7, c = idx & 127;
      if (node < NATOMS){
        int ty = ldt(types, node, tm);
        Xd[idx] = ldf(W1, (size_t)64*128 + (size_t)ty*128 + c, f32);
        Xs[idx] = ldf(W1, (size_t)ty*128 + c, f32);
      } else if (node < NNODES){
        Xd[idx] = 0.f;
      }
    }
  }
}

// ---------- weight-only per-layer work, all 4 layers in one small launch:
//   block b: layer = b/129, sub = b%129.
//   sub==0: Wg = eW@W1c, b1p = b1 + eb@W1c;  sub 1..128: Tt[l] float2 rows. ----------
__global__ void __launch_bounds__(128) k_wt(
    const void* __restrict__ W1, const void* __restrict__ b1,
    const void* __restrict__ eW, const void* __restrict__ eb,
    const int* __restrict__ flag, const float* __restrict__ offc,
    float* __restrict__ Wg, float* __restrict__ b1p, float2* __restrict__ Tt)
{
  __shared__ __attribute__((aligned(16))) float sA[1344];
  __shared__ float sB[192];
  int f32 = flag[0];
  int t = threadIdx.x;
  int b = blockIdx.x;
  int layer = b / 129, sub = b - layer * 129;
  size_t wl  = (size_t)layer*192*128;
  size_t eWo = (size_t)layer*20*64, ebo = (size_t)layer*64;
  size_t b1o = (size_t)layer*128;
  float w[64];
  #pragma unroll
  for (int k = 0; k < 64; k++) w[k] = ldf(W1, wl + (size_t)128*128 + (size_t)k*128 + t, f32);
  for (int i = t; i < 20*64; i += 128) sA[i] = ldf(eW, eWo + i, f32);
  if (sub == 0){
    if (t < 64) sA[1280 + t] = ldf(eb, ebo + t, f32);
    __syncthreads();
    for (int g = 0; g < 20; g++){
      float acc = 0.f;
      #pragma unroll
      for (int k4 = 0; k4 < 16; k4++){
        float4 e = *(const float4*)&sA[g*64 + 4*k4];
        acc = fmaf(e.x, w[4*k4+0], acc); acc = fmaf(e.y, w[4*k4+1], acc);
        acc = fmaf(e.z, w[4*k4+2], acc); acc = fmaf(e.w, w[4*k4+3], acc);
      }
      Wg[layer*20*128 + g*128 + t] = acc;
    }
    float acc = ldf(b1, b1o + t, f32);
    #pragma unroll
    for (int k4 = 0; k4 < 16; k4++){
      float4 e = *(const float4*)&sA[1280 + 4*k4];
      acc = fmaf(e.x, w[4*k4+0], acc); acc = fmaf(e.y, w[4*k4+1], acc);
      acc = fmaf(e.z, w[4*k4+2], acc); acc = fmaf(e.w, w[4*k4+3], acc);
    }
    b1p[layer*128 + t] = acc;
  } else {
    // Tt table rows r0..r0+7 (float2: (f[r],f[r+1])); 9 vals so .y spans rows
    int r0 = (sub - 1) * 8;
    for (int i = t; i < 180; i += 128){
      int row = i / 20, k = i - row*20;
      float d  = (float)(r0 + row) * (5.0f / (float)NT);
      float dd = d - offc[k];
      sB[i] = expf(offc[20 + k] * dd * dd);
    }
    __syncthreads();
    float wg[20];
    #pragma unroll
    for (int gk = 0; gk < 20; gk++){
      float acc = 0.f;
      #pragma unroll
      for (int k4 = 0; k4 < 16; k4++){
        float4 e = *(const float4*)&sA[gk*64 + 4*k4];
        acc = fmaf(e.x, w[4*k4+0], acc); acc = fmaf(e.y, w[4*k4+1], acc);
        acc = fmaf(e.z, w[4*k4+2], acc); acc = fmaf(e.w, w[4*k4+3], acc);
      }
      wg[gk] = acc;
    }
    float v[9];
    #pragma unroll
    for (int r = 0; r < 9; r++){
      float acc = 0.f;
      #pragma unroll
      for (int k = 0; k < 20; k++) acc = fmaf(sB[r*20 + k], wg[k], acc);
      v[r] = acc;
    }
    #pragma unroll
    for (int r = 0; r < 8; r++)
      Tt[(size_t)layer*NT*128 + (size_t)(r0 + r)*128 + t] = make_float2(v[r], v[r+1]);
  }
}

// ---------- aggregation: Sbuf[node][tt] = (1/K) sum_e relu(Xd + Xs[src] + b1p + lerp(Tt,d_e)) ----------
__global__ void __launch_bounds__(256) k_aggr(const float* __restrict__ Xs,
    const float* __restrict__ Xd, const int* __restrict__ nbrA,
    const int* __restrict__ nbrG, const float* __restrict__ node_pos,
    const float2* __restrict__ Tt, const float* __restrict__ b1p,
    float* __restrict__ Sbuf)
{
  __shared__ __attribute__((aligned(16))) int   sN[256];
  __shared__ __attribute__((aligned(16))) float sX[256];
  int t = threadIdx.x;            // 256
  int b = blockIdx.x;
  int KK, node0; const int* nbr;
  if (b < 32){ KK = 8;  node0 = b*32;              nbr = nbrA + b*256; }
  else       { KK = 32; node0 = NATOMS + (b-32)*8; nbr = nbrG + (size_t)(b-32)*256; }
  {
    int src = nbr[t];
    sN[t] = src;
    int node = node0 + ((b < 32) ? (t >> 3) : (t >> 5));
    float dx = node_pos[src*3+0] - node_pos[node*3+0];
    float dy = node_pos[src*3+1] - node_pos[node*3+1];
    float dz = node_pos[src*3+2] - node_pos[node*3+2];
    float dist = fminf(sqrtf(dx*dx + dy*dy + dz*dz), 5.0f);
    sX[t] = dist * ((float)NT / 5.0f);
  }
  int g = t >> 7, tt = t & 127;
  float b1v = b1p[tt];
  __syncthreads();
  float rK = 1.f / KK;
  int nLoc = (b < 32) ? 16 : 4;
  int nbase = g * nLoc;
  for (int n = 0; n < nLoc; n++){
    int node = node0 + nbase + n;
    float zb = Xd[(size_t)node*128 + tt] + b1v;
    float S = 0.f;
    int ebase = (nbase + n) * KK;
    for (int e = 0; e < KK; e += 4){
      int i0 = ebase + e;
      int4   sv = *(const int4*)&sN[i0];
      float4 xv = *(const float4*)&sX[i0];
      int ia0 = (int)xv.x; if (ia0 > NT-1) ia0 = NT-1;
      int ia1 = (int)xv.y; if (ia1 > NT-1) ia1 = NT-1;
      int ia2 = (int)xv.z; if (ia2 > NT-1) ia2 = NT-1;
      int ia3 = (int)xv.w; if (ia3 > NT-1) ia3 = NT-1;
      float f0 = xv.x - (float)ia0;
      float f1 = xv.y - (float)ia1;
      float f2 = xv.z - (float)ia2;
      float f3 = xv.w - (float)ia3;
      float2 w0 = Tt[(size_t)ia0*128 + tt];
      float2 w1 = Tt[(size_t)ia1*128 + tt];
      float2 w2 = Tt[(size_t)ia2*128 + tt];
      float2 w3 = Tt[(size_t)ia3*128 + tt];
      float a0 = zb + Xs[(size_t)sv.x*128 + tt] + fmaf(f0, w0.y - w0.x, w0.x);
      float a1 = zb + Xs[(size_t)sv.y*128 + tt] + fmaf(f1, w1.y - w1.x, w1.x);
      float a2 = zb + Xs[(size_t)sv.z*128 + tt] + fmaf(f2, w2.y - w2.x, w2.x);
      float a3 = zb + Xs[(size_t)sv.w*128 + tt] + fmaf(f3, w3.y - w3.x, w3.x);
      S += fmaxf(a0,0.f) + fmaxf(a1,0.f) + fmaxf(a2,0.f) + fmaxf(a3,0.f);
    }
    Sbuf[(size_t)node*128 + tt] = S * rK;
  }
}

// ---------- merged output + next-layer fold. 248 blocks x 512 thr (8 waves),
//   r13 proven-best structure (304.7 µs): W2/sS staged in LDS once per 32
//   rows (vectorized ushort4/float4), early hin prefetch, w1r loaded AFTER
//   the second barrier (any 64-float array coexisting with the GEMV spills —
//   r10/r12/r14 all confirmed). All FMA orders preserved -> bit-identical. ----------
__global__ void __launch_bounds__(512) k_outfold(const float* __restrict__ hin,
    const float* __restrict__ Sbuf,
    const void* __restrict__ W2, const void* __restrict__ b2,
    const void* __restrict__ lng, const void* __restrict__ lnb,
    size_t w2o, size_t b2o, size_t lno,
    const void* __restrict__ W1, size_t wlNext, int doFold,
    const int* __restrict__ flag,
    float* __restrict__ Xd, float* __restrict__ Xs,
    float* __restrict__ hout, float* __restrict__ out, int writeOut)
{
  __shared__ __attribute__((aligned(16))) float sW2[128*64];   // 32 KB
  __shared__ __attribute__((aligned(16))) float sS[32*128];    // 16 KB
  __shared__ __attribute__((aligned(16))) float sH[32*64];     // 8 KB
  int f32 = flag[0];
  int t = threadIdx.x;            // 512
  int r0 = blockIdx.x * 32;
  int w = t >> 6, c = t & 63;     // 8 waves; each owns rows w*4..w*4+3
  // early independent hin prefetch (this wave's 4 rows; 4 VGPRs)
  float hv0 = hin[(size_t)(r0 + w*4 + 0)*64 + c];
  float hv1 = hin[(size_t)(r0 + w*4 + 1)*64 + c];
  float hv2 = hin[(size_t)(r0 + w*4 + 2)*64 + c];
  float hv3 = hin[(size_t)(r0 + w*4 + 3)*64 + c];
  // vectorized staging: W2 (8192 elems) + sS (4096 floats)
  if (f32){
    const float4* W2v = (const float4*)((const float*)W2 + w2o);
    float4* dW = (float4*)sW2;
    #pragma unroll
    for (int i = 0; i < 4; i++) dW[t + 512*i] = W2v[t + 512*i];
  } else {
    const ushort4* W2v = (const ushort4*)((const bf16*)W2 + w2o);
    float4* dW = (float4*)sW2;
    #pragma unroll
    for (int i = 0; i < 4; i++){
      ushort4 u = W2v[t + 512*i];
      const bf16* pb = (const bf16*)&u;
      dW[t + 512*i] = make_float4(__bfloat162float(pb[0]), __bfloat162float(pb[1]),
                                  __bfloat162float(pb[2]), __bfloat162float(pb[3]));
    }
  }
  {
    const float4* Sv = (const float4*)(Sbuf + (size_t)r0*128);
    float4* dS = (float4*)sS;
    dS[t]       = Sv[t];
    dS[t + 512] = Sv[t + 512];
  }
  float b2v = ldf(b2, b2o + c, f32);
  float gv  = ldf(lng, lno + c, f32);
  float bv  = ldf(lnb, lno + c, f32);
  __syncthreads();
  // ---- out phase, pair 1 (rows w*4, w*4+1) ----
  {
    int rr = w*4;
    float a0 = 0.f, a1 = 0.f;
    const float* s0 = &sS[rr*128];
    const float* s1 = &sS[(rr+1)*128];
    #pragma unroll
    for (int kq = 0; kq < 32; kq++){
      float4 sv0 = *(const float4*)(s0 + 4*kq);
      float4 sv1 = *(const float4*)(s1 + 4*kq);
      a0 = fmaf(sv0.x, sW2[(4*kq+0)*64+c], a0);
      a0 = fmaf(sv0.y, sW2[(4*kq+1)*64+c], a0);
      a0 = fmaf(sv0.z, sW2[(4*kq+2)*64+c], a0);
      a0 = fmaf(sv0.w, sW2[(4*kq+3)*64+c], a0);
      a1 = fmaf(sv1.x, sW2[(4*kq+0)*64+c], a1);
      a1 = fmaf(sv1.y, sW2[(4*kq+1)*64+c], a1);
      a1 = fmaf(sv1.z, sW2[(4*kq+2)*64+c], a1);
      a1 = fmaf(sv1.w, sW2[(4*kq+3)*64+c], a1);
    }
    {
      int node = r0 + rr;
      float x = hv0 + a0 + b2v;
      float s = x;
      #pragma unroll
      for (int m = 1; m < 64; m <<= 1) s += __shfl_xor(s, m);
      float mu = s * (1.f/64.f);
      float d = x - mu;
      float v = d * d;
      #pragma unroll
      for (int m = 1; m < 64; m <<= 1) v += __shfl_xor(v, m);
      v *= (1.f/64.f);
      float o = d / sqrtf(v + 1e-5f) * gv + bv;
      hout[(size_t)node*64 + c] = o;
      sH[rr*64 + c] = o;
      if (writeOut && node >= NATOMS) out[(size_t)(node - NATOMS)*64 + c] = o;
    }
    {
      int node = r0 + rr + 1;
      float x = hv1 + a1 + b2v;
      float s = x;
      #pragma unroll
      for (int m = 1; m < 64; m <<= 1) s += __shfl_xor(s, m);
      float mu = s * (1.f/64.f);
      float d = x - mu;
      float v = d * d;
      #pragma unroll
      for (int m = 1; m < 64; m <<= 1) v += __shfl_xor(v, m);
      v *= (1.f/64.f);
      float o = d / sqrtf(v + 1e-5f) * gv + bv;
      hout[(size_t)node*64 + c] = o;
      sH[(rr+1)*64 + c] = o;
      if (writeOut && node >= NATOMS) out[(size_t)(node - NATOMS)*64 + c] = o;
    }
  }
  // ---- out phase, pair 2 (rows w*4+2, w*4+3) ----
  {
    int rr = w*4 + 2;
    float a0 = 0.f, a1 = 0.f;
    const float* s0 = &sS[rr*128];
    const float* s1 = &sS[(rr+1)*128];
    #pragma unroll
    for (int kq = 0; kq < 32; kq++){
      float4 sv0 = *(const float4*)(s0 + 4*kq);
      float4 sv1 = *(const float4*)(s1 + 4*kq);
      a0 = fmaf(sv0.x, sW2[(4*kq+0)*64+c], a0);
      a0 = fmaf(sv0.y, sW2[(4*kq+1)*64+c], a0);
      a0 = fmaf(sv0.z, sW2[(4*kq+2)*64+c], a0);
      a0 = fmaf(sv0.w, sW2[(4*kq+3)*64+c], a0);
      a1 = fmaf(sv1.x, sW2[(4*kq+0)*64+c], a1);
      a1 = fmaf(sv1.y, sW2[(4*kq+1)*64+c], a1);
      a1 = fmaf(sv1.z, sW2[(4*kq+2)*64+c], a1);
      a1 = fmaf(sv1.w, sW2[(4*kq+3)*64+c], a1);
    }
    {
      int node = r0 + rr;
      float x = hv2 + a0 + b2v;
      float s = x;
      #pragma unroll
      for (int m = 1; m < 64; m <<= 1) s += __shfl_xor(s, m);
      float mu = s * (1.f/64.f);
      float d = x - mu;
      float v = d * d;
      #pragma unroll
      for (int m = 1; m < 64; m <<= 1) v += __shfl_xor(v, m);
      v *= (1.f/64.f);
      float o = d / sqrtf(v + 1e-5f) * gv + bv;
      hout[(size_t)node*64 + c] = o;
      sH[rr*64 + c] = o;
      if (writeOut && node >= NATOMS) out[(size_t)(node - NATOMS)*64 + c] = o;
    }
    {
      int node = r0 + rr + 1;
      float x = hv3 + a1 + b2v;
      float s = x;
      #pragma unroll
      for (int m = 1; m < 64; m <<= 1) s += __shfl_xor(s, m);
      float mu = s * (1.f/64.f);
      float d = x - mu;
      float v = d * d;
      #pragma unroll
      for (int m = 1; m < 64; m <<= 1) v += __shfl_xor(v, m);
      v *= (1.f/64.f);
      float o = d / sqrtf(v + 1e-5f) * gv + bv;
      hout[(size_t)node*64 + c] = o;
      sH[(rr+1)*64 + c] = o;
      if (writeOut && node >= NATOMS) out[(size_t)(node - NATOMS)*64 + c] = o;
    }
  }
  if (!doFold) return;
  __syncthreads();
  int col = t & 127, q = t >> 7;   // 4 quarters x 8 rows = 32 rows
  int rbase = q * 8;
  {
    float w1r[64];
    #pragma unroll
    for (int k = 0; k < 64; k++)
      w1r[k] = ldf(W1, wlNext + (size_t)64*128 + (size_t)k*128 + col, f32);
    for (int r = rbase; r < rbase + 8; r += 4){
      float a0 = 0.f, a1 = 0.f, a2 = 0.f, a3 = 0.f;
      #pragma unroll
      for (int k4 = 0; k4 < 16; k4++){
        float4 v0 = *(const float4*)&sH[(r+0)*64 + 4*k4];
        float4 v1 = *(const float4*)&sH[(r+1)*64 + 4*k4];
        float4 v2 = *(const float4*)&sH[(r+2)*64 + 4*k4];
        float4 v3 = *(const float4*)&sH[(r+3)*64 + 4*k4];
        a0 = fmaf(v0.x, w1r[4*k4+0], a0); a0 = fmaf(v0.y, w1r[4*k4+1], a0);
        a0 = fmaf(v0.z, w1r[4*k4+2], a0); a0 = fmaf(v0.w, w1r[4*k4+3], a0);
        a1 = fmaf(v1.x, w1r[4*k4+0], a1); a1 = fmaf(v1.y, w1r[4*k4+1], a1);
        a1 = fmaf(v1.z, w1r[4*k4+2], a1); a1 = fmaf(v1.w, w1r[4*k4+3], a1);
        a2 = fmaf(v2.x, w1r[4*k4+0], a2); a2 = fmaf(v2.y, w1r[4*k4+1], a2);
        a2 = fmaf(v2.z, w1r[4*k4+2], a2); a2 = fmaf(v2.w, w1r[4*k4+3], a2);
        a3 = fmaf(v3.x, w1r[4*k4+0], a3); a3 = fmaf(v3.y, w1r[4*k4+1], a3);
        a3 = fmaf(v3.z, w1r[4*k4+2], a3); a3 = fmaf(v3.w, w1r[4*k4+3], a3);
      }
      Xd[(size_t)(r0 + r + 0)*128 + col] = a0;
      Xd[(size_t)(r0 + r + 1)*128 + col] = a1;
      Xd[(size_t)(r0 + r + 2)*128 + col] = a2;
      Xd[(size_t)(r0 + r + 3)*128 + col] = a3;
    }
  }
  if (blockIdx.x < 32){
    float w1s[64];
    #pragma unroll
    for (int k = 0; k < 64; k++)
      w1s[k] = ldf(W1, wlNext + (size_t)k*128 + col, f32);
    for (int r = rbase; r < rbase + 8; r += 4){
      float a0 = 0.f, a1 = 0.f, a2 = 0.f, a3 = 0.f;
      #pragma unroll
      for (int k4 = 0; k4 < 16; k4++){
        float4 v0 = *(const float4*)&sH[(r+0)*64 + 4*k4];
        float4 v1 = *(const float4*)&sH[(r+1)*64 + 4*k4];
        float4 v2 = *(const float4*)&sH[(r+2)*64 + 4*k4];
        float4 v3 = *(const float4*)&sH[(r+3)*64 + 4*k4];
        a0 = fmaf(v0.x, w1s[4*k4+0], a0); a0 = fmaf(v0.y, w1s[4*k4+1], a0);
        a0 = fmaf(v0.z, w1s[4*k4+2], a0); a0 = fmaf(v0.w, w1s[4*k4+3], a0);
        a1 = fmaf(v1.x, w1s[4*k4+0], a1); a1 = fmaf(v1.y, w1s[4*k4+1], a1);
        a1 = fmaf(v1.z, w1s[4*k4+2], a1); a1 = fmaf(v1.w, w1s[4*k4+3], a1);
        a2 = fmaf(v2.x, w1s[4*k4+0], a2); a2 = fmaf(v2.y, w1s[4*k4+1], a2);
        a2 = fmaf(v2.z, w1s[4*k4+2], a2); a2 = fmaf(v2.w, w1s[4*k4+3], a2);
        a3 = fmaf(v3.x, w1s[4*k4+0], a3); a3 = fmaf(v3.y, w1s[4*k4+1], a3);
        a3 = fmaf(v3.z, w1s[4*k4+2], a3); a3 = fmaf(v3.w, w1s[4*k4+3], a3);
      }
      Xs[(size_t)(r0 + r + 0)*128 + col] = a0;
      Xs[(size_t)(r0 + r + 1)*128 + col] = a1;
      Xs[(size_t)(r0 + r + 2)*128 + col] = a2;
      Xs[(size_t)(r0 + r + 3)*128 + col] = a3;
    }
  }
}

extern "C" void kernel_launch(void* const* d_in, const int* in_sizes, int n_in,
                              void* d_out, int out_size, void* d_ws, size_t ws_size,
                              hipStream_t stream) {
  const void* pos    = d_in[0];
  const void* types  = d_in[1];
  // d_in[2] = batch (unused by the math)
  const void* edge_W = d_in[3];
  const void* edge_b = d_in[4];
  const void* W1     = d_in[5];
  const void* b1     = d_in[6];
  const void* W2     = d_in[7];
  const void* b2     = d_in[8];
  const void* lng    = d_in[9];
  const void* lnb    = d_in[10];

  const size_t NEED = (size_t)20 * 1024 * 1024;
  char* w = (ws_size >= NEED) ? (char*)d_ws : (char*)g_buf;
  if (w == nullptr) w = (char*)d_ws;   // last resort

  size_t o = 0;
  auto alloc = [&](size_t bytes)->char*{
    char* r = w + o; o = (o + bytes + 255) & ~(size_t)255; return r;
  };
  float*  node_pos = (float*) alloc((size_t)NNODES*3*4);
  float*  hA       = (float*) alloc((size_t)NNODES*CODE*4);
  float*  hB       = (float*) alloc((size_t)NNODES*CODE*4);
  float*  Xs       = (float*) alloc((size_t)NATOMS*HID*4);
  float*  Xd       = (float*) alloc((size_t)NNODES*HID*4);
  float*  Sbuf     = (float*) alloc((size_t)NNODES*HID*4);
  int*    nbrA     = (int*)   alloc((size_t)NATOMS*KA*4);
  int*    nbrG     = (int*)   alloc((size_t)NGRID*KG*4);
  float*  offc     = (float*) alloc(64*4);
  float*  Wg       = (float*) alloc((size_t)4*20*HID*4);
  float*  b1p      = (float*) alloc((size_t)4*HID*4);
  int*    flag     = (int*)   alloc(64*4);
  float2* Tt       = (float2*)alloc((size_t)4*NT*HID*8);   // 4 layers x 1.05 MB

  k0<<<2, 256, 0, stream>>>((const unsigned short*)pos,
                            (const unsigned short*)types, flag, offc);
  k_wt<<<4*129, 128, 0, stream>>>(W1, b1, edge_W, edge_b, flag, offc,
                                  Wg, b1p, Tt);
  // k_pre includes the layer-0 fold gather in blocks 3968..4959
  k_pre<<<3968 + 992, 256, 0, stream>>>(pos, types, flag, node_pos, hA,
                                        nbrA, nbrG, W1, Xd, Xs);

  float* hin = hA; float* hout = hB;
  for (int l = 0; l < 4; l++){
    size_t w2o = (size_t)l*128*64;
    size_t b2o = (size_t)l*64, lno = (size_t)l*64;
    size_t wlN = (size_t)(l+1)*192*128;
    k_aggr<<<32 + NGRID/8, 256, 0, stream>>>(Xs, Xd, nbrA, nbrG, node_pos,
                                             Tt + (size_t)l*NT*HID, b1p + l*HID,
                                             Sbuf);
    k_outfold<<<NNODES/32, 512, 0, stream>>>(hin, Sbuf, W2, b2, lng, lnb,
                                             w2o, b2o, lno,
                                             W1, wlN, (l < 3) ? 1 : 0,
                                             flag, Xd, Xs,
                                             hout, (float*)d_out, (l == 3) ? 1 : 0);
    float* tmp = hin; hin = hout; hout = tmp;
  }
}